// Round 10
// baseline (1158.809 us; speedup 1.0000x reference)
//
#include <hip/hip_runtime.h>
#include <hip/hip_bf16.h>
#include <hip/hip_cooperative_groups.h>
#include <math.h>

namespace cg = cooperative_groups;

#define NN 10000      // nodes
#define NE 160000     // edges
#define NF 9          // atom features
#define VOCAB 128
#define D 128
#define NH 4          // heads
#define C 128
#define HC 512        // NH*C
#define NCLS 10
#define NL 3

#define NEG_BIG (-1e30f)   // finite -inf substitute
#define MB 512             // mega grid blocks
#define NCHUNK 20          // nodes per block in scan/pool (512*20 >= 10000)

typedef __attribute__((ext_vector_type(8))) short bf16x8;
typedef __attribute__((ext_vector_type(4))) float f32x4;

__device__ __forceinline__ unsigned short f2bf(float f) {
    unsigned u = __float_as_uint(f);
    unsigned r = ((u >> 16) & 1u) + 0x7FFFu;
    return (unsigned short)((u + r) >> 16);
}
__device__ __forceinline__ float bf2f(unsigned short h) {
    return __uint_as_float(((unsigned)h) << 16);
}

// ===================== mega-kernel (cooperative) =====================

struct MegaParams {
    const int* feats; const int* srcp; const int* dstp;
    const float* emb; const float* W; const float* asrcW; const float* adstW;
    const float* bias; const float* Wc; const float* bc;
    float* out;
    unsigned short *aggh, *aggl;
    float *xb0, *xb1, *asrc, *adst;
    int *deg, *rowst, *cursor, *csrsrc, *blocksum, *blockoff;
    float *wsrcb, *wdstb;
    unsigned short *Bth, *Btl;
    float *Mhead, *b10, *p512;
};

// per-dst softmax + aggregation; 2 nodes/block (128-thr subgroups), chunk loop on pair-max deg
__device__ __forceinline__ void run_agg(
    const int* __restrict__ csr, const int* __restrict__ rowstA,
    const int* __restrict__ degA, const float* __restrict__ asr,
    const float* __restrict__ adr, const float* __restrict__ X,
    unsigned* __restrict__ aggh, unsigned* __restrict__ aggl,
    int tid, int bid,
    float* smax, float* sinv, float* lal, int* lsrc, int* sdeg) {
    int sub = tid >> 7, tt = tid & 127;
    for (int base = 0; base < NN; base += MB * 2) {
        int n = base + bid * 2 + sub;
        bool valid = n < NN;
        int deg = valid ? degA[n] : 0;
        int start = valid ? rowstA[n] : 0;
        int h = tt >> 5, i = tt & 31;           // h in 0..3 within subgroup
        float ad_h = valid ? adr[n * NH + h] : 0.f;
        float mx = NEG_BIG;
        for (int j = i; j < deg; j += 32) {
            int s = csr[start + j];
            float v = asr[s * NH + h] + ad_h;
            v = v >= 0.f ? v : 0.2f * v;
            mx = fmaxf(mx, v);
        }
#pragma unroll
        for (int off = 16; off; off >>= 1) mx = fmaxf(mx, __shfl_xor(mx, off));
        if (i == 0) smax[sub * NH + h] = mx;
        __syncthreads();
        float m = smax[sub * NH + h];
        float ss = 0.f;
        for (int j = i; j < deg; j += 32) {
            int s = csr[start + j];
            float v = asr[s * NH + h] + ad_h;
            v = v >= 0.f ? v : 0.2f * v;
            ss += __expf(v - m);
        }
#pragma unroll
        for (int off = 16; off; off >>= 1) ss += __shfl_xor(ss, off);
        if (i == 0) sinv[sub * NH + h] = 0.25f / (ss + 1e-16f);
        if (tt == 0) sdeg[sub] = deg;
        __syncthreads();

        float fm0 = smax[sub * NH + 0], fm1 = smax[sub * NH + 1];
        float fm2 = smax[sub * NH + 2], fm3 = smax[sub * NH + 3];
        float fi0 = sinv[sub * NH + 0], fi1 = sinv[sub * NH + 1];
        float fi2 = sinv[sub * NH + 2], fi3 = sinv[sub * NH + 3];
        float a0 = 0.f, a1 = 0.f, a2 = 0.f, a3 = 0.f;
        if (valid) {
            float4 av = *(const float4*)(adr + n * NH);
            a0 = av.x; a1 = av.y; a2 = av.z; a3 = av.w;
        }
        int dmax = sdeg[0] > sdeg[1] ? sdeg[0] : sdeg[1];
        float acc0 = 0.f, acc1 = 0.f, acc2 = 0.f, acc3 = 0.f;
        for (int cb = 0; cb < dmax; cb += 128) {
            int cl = deg - cb; if (cl > 128) cl = 128;
            if (tt < cl) {
                int sn = csr[start + cb + tt];
                float4 av = *(const float4*)(asr + sn * NH);
                float v0 = av.x + a0; v0 = v0 >= 0.f ? v0 : 0.2f * v0;
                float v1 = av.y + a1; v1 = v1 >= 0.f ? v1 : 0.2f * v1;
                float v2 = av.z + a2; v2 = v2 >= 0.f ? v2 : 0.2f * v2;
                float v3 = av.w + a3; v3 = v3 >= 0.f ? v3 : 0.2f * v3;
                float* lp = lal + (size_t)(sub * 128 + tt) * NH;
                lp[0] = __expf(v0 - fm0) * fi0;
                lp[1] = __expf(v1 - fm1) * fi1;
                lp[2] = __expf(v2 - fm2) * fi2;
                lp[3] = __expf(v3 - fm3) * fi3;
                lsrc[sub * 128 + tt] = sn;
            }
            __syncthreads();
#pragma unroll 4
            for (int j = 0; j < cl; ++j) {
                float xv = X[(size_t)lsrc[sub * 128 + j] * D + tt];
                float4 w = *(const float4*)(lal + (size_t)(sub * 128 + j) * NH);
                acc0 += w.x * xv;
                acc1 += w.y * xv;
                acc2 += w.z * xv;
                acc3 += w.w * xv;
            }
            __syncthreads();
        }
        if (valid) {
            unsigned short h0 = f2bf(acc0), h1 = f2bf(acc1), h2 = f2bf(acc2), h3 = f2bf(acc3);
            unsigned short l0 = f2bf(acc0 - bf2f(h0)), l1 = f2bf(acc1 - bf2f(h1));
            unsigned short l2 = f2bf(acc2 - bf2f(h2)), l3 = f2bf(acc3 - bf2f(h3));
            size_t bofs = ((size_t)n * HC + tt * 4) >> 1;
            uint2 uh = make_uint2((unsigned)h0 | ((unsigned)h1 << 16),
                                  (unsigned)h2 | ((unsigned)h3 << 16));
            uint2 ul = make_uint2((unsigned)l0 | ((unsigned)l1 << 16),
                                  (unsigned)l2 | ((unsigned)l3 << 16));
            *(uint2*)((unsigned*)aggh + bofs) = uh;
            *(uint2*)((unsigned*)aggl + bofs) = ul;
        }
        __syncthreads();   // protect smax/sinv/sdeg reuse next iteration (dmax may be 0)
    }
}

// split-bf16 MFMA GEMM: 4 tiles/block (one per wave); tile = 16 rows x 64 cols
__device__ __forceinline__ void run_gemm(
    const unsigned short* __restrict__ Ah, const unsigned short* __restrict__ Al,
    const unsigned short* __restrict__ Bth, const unsigned short* __restrict__ Btl,
    const float* __restrict__ bias, float* __restrict__ Out,
    int tid, int bid) {
    int tile = bid * 4 + (tid >> 6);
    if (tile >= (NN / 16) * 2) return;
    int lane = tid & 63;
    int m0 = (tile >> 1) * 16;
    int n0 = (tile & 1) * 64;
    int r = lane & 15;
    int g = lane >> 4;

    const bf16x8* ah = (const bf16x8*)(Ah + (size_t)(m0 + r) * HC + g * 8);
    const bf16x8* al = (const bf16x8*)(Al + (size_t)(m0 + r) * HC + g * 8);
    const bf16x8* bh0 = (const bf16x8*)(Bth + (size_t)(n0 + 0 * 16 + r) * HC + g * 8);
    const bf16x8* bh1 = (const bf16x8*)(Bth + (size_t)(n0 + 1 * 16 + r) * HC + g * 8);
    const bf16x8* bh2 = (const bf16x8*)(Bth + (size_t)(n0 + 2 * 16 + r) * HC + g * 8);
    const bf16x8* bh3 = (const bf16x8*)(Bth + (size_t)(n0 + 3 * 16 + r) * HC + g * 8);
    const bf16x8* bl0 = (const bf16x8*)(Btl + (size_t)(n0 + 0 * 16 + r) * HC + g * 8);
    const bf16x8* bl1 = (const bf16x8*)(Btl + (size_t)(n0 + 1 * 16 + r) * HC + g * 8);
    const bf16x8* bl2 = (const bf16x8*)(Btl + (size_t)(n0 + 2 * 16 + r) * HC + g * 8);
    const bf16x8* bl3 = (const bf16x8*)(Btl + (size_t)(n0 + 3 * 16 + r) * HC + g * 8);

    f32x4 acc[4];
#pragma unroll
    for (int q = 0; q < 4; ++q) acc[q] = (f32x4){0.f, 0.f, 0.f, 0.f};

#pragma unroll 2
    for (int ks = 0; ks < HC / 32; ++ks) {
        bf16x8 a_h = ah[ks * 4];
        bf16x8 a_l = al[ks * 4];
        bf16x8 b;
        b = bh0[ks * 4];
        acc[0] = __builtin_amdgcn_mfma_f32_16x16x32_bf16(a_h, b, acc[0], 0, 0, 0);
        acc[0] = __builtin_amdgcn_mfma_f32_16x16x32_bf16(a_l, b, acc[0], 0, 0, 0);
        b = bl0[ks * 4];
        acc[0] = __builtin_amdgcn_mfma_f32_16x16x32_bf16(a_h, b, acc[0], 0, 0, 0);
        b = bh1[ks * 4];
        acc[1] = __builtin_amdgcn_mfma_f32_16x16x32_bf16(a_h, b, acc[1], 0, 0, 0);
        acc[1] = __builtin_amdgcn_mfma_f32_16x16x32_bf16(a_l, b, acc[1], 0, 0, 0);
        b = bl1[ks * 4];
        acc[1] = __builtin_amdgcn_mfma_f32_16x16x32_bf16(a_h, b, acc[1], 0, 0, 0);
        b = bh2[ks * 4];
        acc[2] = __builtin_amdgcn_mfma_f32_16x16x32_bf16(a_h, b, acc[2], 0, 0, 0);
        acc[2] = __builtin_amdgcn_mfma_f32_16x16x32_bf16(a_l, b, acc[2], 0, 0, 0);
        b = bl2[ks * 4];
        acc[2] = __builtin_amdgcn_mfma_f32_16x16x32_bf16(a_h, b, acc[2], 0, 0, 0);
        b = bh3[ks * 4];
        acc[3] = __builtin_amdgcn_mfma_f32_16x16x32_bf16(a_h, b, acc[3], 0, 0, 0);
        acc[3] = __builtin_amdgcn_mfma_f32_16x16x32_bf16(a_l, b, acc[3], 0, 0, 0);
        b = bl3[ks * 4];
        acc[3] = __builtin_amdgcn_mfma_f32_16x16x32_bf16(a_h, b, acc[3], 0, 0, 0);
    }

#pragma unroll
    for (int q = 0; q < 4; ++q) {
#pragma unroll
        for (int i = 0; i < 4; ++i) {
            int row = m0 + g * 4 + i;
            int col = n0 + q * 16 + r;
            float v = acc[q][i] + bias[col];
            float u = 0.7978845608028654f * (v + 0.044715f * v * v * v);
            v = 0.5f * v * (1.f + tanhf(u));
            Out[(size_t)row * D + col] = v;
        }
    }
}

// alpha dots: 4 nodes/block (64-thr groups)
__device__ __forceinline__ void run_alphas(
    const float* __restrict__ X, const float* __restrict__ wsrc,
    const float* __restrict__ wdst, float* __restrict__ asrc,
    float* __restrict__ adst, int tid, int bid) {
    int lane = tid & 63;
    for (int base = 0; base < NN; base += MB * 4) {
        int n = base + bid * 4 + (tid >> 6);
        if (n >= NN) continue;
        float x0 = X[n * D + lane], x1 = X[n * D + lane + 64];
#pragma unroll
        for (int h = 0; h < NH; ++h) {
            float s = x0 * wsrc[h * D + lane] + x1 * wsrc[h * D + lane + 64];
            float d = x0 * wdst[h * D + lane] + x1 * wdst[h * D + lane + 64];
#pragma unroll
            for (int off = 32; off; off >>= 1) {
                s += __shfl_down(s, off);
                d += __shfl_down(d, off);
            }
            if (lane == 0) { asrc[n * NH + h] = s; adst[n * NH + h] = d; }
        }
    }
}

__global__ __launch_bounds__(256, 2)
void mega(MegaParams p) {
    cg::grid_group grid = cg::this_grid();
    const int tid = threadIdx.x;
    const int bid = blockIdx.x;
    const int gtid = bid * 256 + tid;
    const int gsz = MB * 256;

    __shared__ int s_scan[256];
    __shared__ int s_f[2][NF];
    __shared__ float s_part[2][2][8];
    __shared__ float s_smax[2 * NH];
    __shared__ float s_sinv[2 * NH];
    __shared__ float s_lal[2 * 128 * NH];
    __shared__ int s_lsrc[2 * 128];
    __shared__ int s_sdeg[2];

    // ---- P0: zero deg ----
    for (int i = gtid; i < NN; i += gsz) p.deg[i] = 0;
    grid.sync();

    // ---- P1: hist ----
    for (int e = gtid; e < NE; e += gsz) atomicAdd(&p.deg[p.dstp[e]], 1);
    grid.sync();

    // ---- P2a: per-block chunk sums ----
    {
        int n0 = bid * NCHUNK;
        int v = 0;
        if (tid < NCHUNK && n0 + tid < NN) v = p.deg[n0 + tid];
        if (tid < 64) {
#pragma unroll
            for (int off = 32; off; off >>= 1) v += __shfl_down(v, off);
            if (tid == 0) p.blocksum[bid] = v;
        }
    }
    grid.sync();

    // ---- P2b: block 0 scans 512 blocksums ----
    if (bid == 0) {
        int a = p.blocksum[2 * tid], b2 = p.blocksum[2 * tid + 1];
        int pr = a + b2;
        s_scan[tid] = pr;
        __syncthreads();
        for (int off = 1; off < 256; off <<= 1) {
            int val = (tid >= off) ? s_scan[tid - off] : 0;
            __syncthreads();
            s_scan[tid] += val;
            __syncthreads();
        }
        int ep = s_scan[tid] - pr;
        p.blockoff[2 * tid] = ep;
        p.blockoff[2 * tid + 1] = ep + a;
    }
    grid.sync();

    // ---- P2c: local exclusive scan -> rowst/cursor; plus weight prep ----
    if (tid == 0) {
        int run = p.blockoff[bid];
        int n0 = bid * NCHUNK;
        for (int i = 0; i < NCHUNK; ++i) {
            int idx = n0 + i;
            if (idx < NN) { p.rowst[idx] = run; p.cursor[idx] = run; run += p.deg[idx]; }
        }
    }
    for (int u = bid; u < 24 + 512 + 20; u += MB) {
        if (u < 24) {                         // att fold: wsrc/wdst
            if (tid < 128) {
                int k = tid;
                int l = u >> 3, r = u & 7, h = r >> 1, side = r & 1;
                const float* av = (side ? p.adstW : p.asrcW) + (size_t)(l * NH + h) * C;
                const float* wrow = p.W + (size_t)l * D * HC + (size_t)k * HC + h * C;
                float acc = 0.f;
#pragma unroll 4
                for (int c = 0; c < C; ++c) acc += wrow[c] * av[c];
                float* o = (side ? p.wdstb : p.wsrcb) + (size_t)(l * NH + h) * D + k;
                *o = acc;
            }
        } else if (u < 536) {                 // W split: j = d*4 + h, bf16 hi/lo
            int w = u - 24;
            int l = w >> 8, c = (w & 255) >> 1, jh = w & 1;
            int j = jh * 256 + tid;
            float v = p.W[(size_t)l * D * HC + (size_t)(j >> 2) * HC + (j & 3) * C + c];
            unsigned short h = f2bf(v);
            unsigned short lo = f2bf(v - bf2f(h));
            size_t o = (size_t)(l * 128 + c) * HC + j;
            p.Bth[o] = h;
            p.Btl[o] = lo;
        } else {                              // head: M, b10, zero p512
            int hu = u - 536;
            int k = hu >> 1, jh = hu & 1;
            int j = jh * 256 + tid;
            const float* W3 = p.W + (size_t)2 * D * HC;
            const float* wrow = W3 + (size_t)(j >> 2) * HC + (j & 3) * C;
            float acc = 0.f;
#pragma unroll 4
            for (int c = 0; c < C; ++c) acc += wrow[c] * p.Wc[c * NCLS + k];
            p.Mhead[(size_t)k * HC + j] = acc;
            if (k == 0) p.p512[j] = 0.f;
            if (j == 0) {
                const float* bias3 = p.bias + (size_t)2 * D;
                float bsum = p.bc[k];
                for (int c = 0; c < C; ++c) bsum += bias3[c] * p.Wc[c * NCLS + k];
                p.b10[k] = bsum;
            }
        }
    }
    grid.sync();

    // ---- P3: scatter + encoder(+layer-0 alphas) ----
    for (int e = gtid; e < NE; e += gsz) {
        int pos = atomicAdd(&p.cursor[p.dstp[e]], 1);
        p.csrsrc[pos] = p.srcp[e];
    }
    {
        int sub = tid >> 7, tt = tid & 127;
        for (int base = 0; base < NN; base += MB * 2) {
            int n = base + bid * 2 + sub;
            bool valid = n < NN;
            if (valid && tt < NF) s_f[sub][tt] = p.feats[n * NF + tt];
            __syncthreads();
            float dots[8];
#pragma unroll
            for (int k = 0; k < 8; ++k) dots[k] = 0.f;
            if (valid) {
                float acc = 0.f;
#pragma unroll
                for (int i = 0; i < NF; ++i)
                    acc += p.emb[(i * VOCAB + s_f[sub][i]) * D + tt];
                p.xb0[n * D + tt] = acc;
#pragma unroll
                for (int h = 0; h < NH; ++h) {
                    dots[h]     = acc * p.wsrcb[h * D + tt];
                    dots[4 + h] = acc * p.wdstb[h * D + tt];
                }
            }
#pragma unroll
            for (int off = 32; off; off >>= 1)
#pragma unroll
                for (int k = 0; k < 8; ++k) dots[k] += __shfl_down(dots[k], off);
            if ((tt & 63) == 0) {
#pragma unroll
                for (int k = 0; k < 8; ++k) s_part[sub][tt >> 6][k] = dots[k];
            }
            __syncthreads();
            if (valid && tt < 8) {
                float v = s_part[sub][0][tt] + s_part[sub][1][tt];
                if (tt < 4) p.asrc[n * NH + tt] = v;
                else        p.adst[n * NH + (tt - 4)] = v;
            }
            __syncthreads();
        }
    }
    grid.sync();

    // ---- layer 0 ----
    run_agg(p.csrsrc, p.rowst, p.deg, p.asrc, p.adst, p.xb0,
            (unsigned*)p.aggh, (unsigned*)p.aggl, tid, bid,
            s_smax, s_sinv, s_lal, s_lsrc, s_sdeg);
    grid.sync();
    run_gemm(p.aggh, p.aggl, p.Bth, p.Btl, p.bias, p.xb1, tid, bid);
    grid.sync();
    run_alphas(p.xb1, p.wsrcb + (size_t)1 * NH * D, p.wdstb + (size_t)1 * NH * D,
               p.asrc, p.adst, tid, bid);
    grid.sync();

    // ---- layer 1 ----
    run_agg(p.csrsrc, p.rowst, p.deg, p.asrc, p.adst, p.xb1,
            (unsigned*)p.aggh, (unsigned*)p.aggl, tid, bid,
            s_smax, s_sinv, s_lal, s_lsrc, s_sdeg);
    grid.sync();
    run_gemm(p.aggh, p.aggl, p.Bth + (size_t)128 * HC, p.Btl + (size_t)128 * HC,
             p.bias + (size_t)1 * D, p.xb0, tid, bid);
    grid.sync();
    run_alphas(p.xb0, p.wsrcb + (size_t)2 * NH * D, p.wdstb + (size_t)2 * NH * D,
               p.asrc, p.adst, tid, bid);
    grid.sync();

    // ---- layer 2: agg then pool in agg-space ----
    run_agg(p.csrsrc, p.rowst, p.deg, p.asrc, p.adst, p.xb0,
            (unsigned*)p.aggh, (unsigned*)p.aggl, tid, bid,
            s_smax, s_sinv, s_lal, s_lsrc, s_sdeg);
    grid.sync();
    {
        int n0 = bid * NCHUNK;
        float a0 = 0.f, a1 = 0.f;
        for (int i = 0; i < NCHUNK; ++i) {
            int idx = n0 + i;
            if (idx < NN) {
                a0 += bf2f(p.aggh[(size_t)idx * HC + tid]) + bf2f(p.aggl[(size_t)idx * HC + tid]);
                a1 += bf2f(p.aggh[(size_t)idx * HC + tid + 256]) + bf2f(p.aggl[(size_t)idx * HC + tid + 256]);
            }
        }
        atomicAdd(p.p512 + tid, a0);
        atomicAdd(p.p512 + tid + 256, a1);
    }
    grid.sync();

    // ---- final head: block 0, 16-lane groups per class ----
    if (bid == 0) {
        int k = tid >> 4, i = tid & 15;
        if (k < NCLS) {
            float acc = 0.f;
#pragma unroll 8
            for (int q = 0; q < HC / 16; ++q) {
                int j = i + q * 16;
                acc += p.p512[j] * p.Mhead[(size_t)k * HC + j];
            }
#pragma unroll
            for (int off = 8; off; off >>= 1) acc += __shfl_down(acc, off, 16);
            if (i == 0) p.out[k] = p.b10[k] + acc * (1.0f / NN);
        }
    }
}

// ===================== fallback multi-kernel path (R9, proven) =====================

__global__ __launch_bounds__(256)
void hist(const int* __restrict__ dst, int* __restrict__ deg) {
    int e = blockIdx.x * 256 + threadIdx.x;
    if (e < NE) atomicAdd(&deg[dst[e]], 1);
}

#define SCAN_T 1024
#define SCAN_PER ((NN + SCAN_T - 1) / SCAN_T)
__global__ __launch_bounds__(SCAN_T)
void scan_deg(const int* __restrict__ deg, int* __restrict__ rowstart,
              int* __restrict__ cursor) {
    __shared__ int part[SCAN_T];
    int t = threadIdx.x;
    int base = t * SCAN_PER;
    int vals[SCAN_PER];
    int loc = 0;
#pragma unroll
    for (int i = 0; i < SCAN_PER; ++i) {
        int idx = base + i;
        int v = (idx < NN) ? deg[idx] : 0;
        vals[i] = v;
        loc += v;
    }
    part[t] = loc;
    __syncthreads();
    for (int off = 1; off < SCAN_T; off <<= 1) {
        int y = (t >= off) ? part[t - off] : 0;
        __syncthreads();
        part[t] += y;
        __syncthreads();
    }
    int run = part[t] - loc;
#pragma unroll
    for (int i = 0; i < SCAN_PER; ++i) {
        int idx = base + i;
        if (idx < NN) { rowstart[idx] = run; cursor[idx] = run; }
        run += vals[i];
    }
}

__global__ __launch_bounds__(256)
void scatter(const int* __restrict__ src, const int* __restrict__ dst,
             int* __restrict__ cursor, int* __restrict__ csr_src) {
    int e = blockIdx.x * 256 + threadIdx.x;
    if (e < NE) {
        int p = atomicAdd(&cursor[dst[e]], 1);
        csr_src[p] = src[e];
    }
}

__global__ __launch_bounds__(512)
void prep_all(const float* __restrict__ W, const float* __restrict__ as_,
              const float* __restrict__ ad_, const float* __restrict__ Wc,
              const float* __restrict__ biasA, const float* __restrict__ bc,
              float* __restrict__ wsrc, float* __restrict__ wdst,
              unsigned short* __restrict__ Bth, unsigned short* __restrict__ Btl,
              float* __restrict__ M, float* __restrict__ b10,
              float* __restrict__ p512) {
    int b = blockIdx.x;
    if (b < 24) {
        int k = threadIdx.x;
        if (k >= 128) return;
        int l = b >> 3, r = b & 7, h = r >> 1, side = r & 1;
        const float* av = (side ? ad_ : as_) + (size_t)(l * NH + h) * C;
        const float* wrow = W + (size_t)l * D * HC + (size_t)k * HC + h * C;
        float acc = 0.f;
#pragma unroll 4
        for (int c = 0; c < C; ++c) acc += wrow[c] * av[c];
        float* o = (side ? wdst : wsrc) + (size_t)(l * NH + h) * D + k;
        *o = acc;
    } else if (b < 280) {
        int bb = b - 24;
        int l = bb >> 7, c = bb & 127;
        int j = threadIdx.x;
        float v = W[(size_t)l * D * HC + (size_t)(j >> 2) * HC + (j & 3) * C + c];
        unsigned short h = f2bf(v);
        unsigned short lo = f2bf(v - bf2f(h));
        size_t o = (size_t)(l * 128 + c) * HC + j;
        Bth[o] = h;
        Btl[o] = lo;
    } else {
        int k = b - 280;
        int j = threadIdx.x;
        const float* W3 = W + (size_t)2 * D * HC;
        const float* bias3 = biasA + (size_t)2 * D;
        const float* wrow = W3 + (size_t)(j >> 2) * HC + (j & 3) * C;
        float acc = 0.f;
#pragma unroll 4
        for (int c = 0; c < C; ++c) acc += wrow[c] * Wc[c * NCLS + k];
        M[(size_t)k * HC + j] = acc;
        if (k == 0) p512[j] = 0.f;
        if (j == 0) {
            float bsum = bc[k];
            for (int c = 0; c < C; ++c) bsum += bias3[c] * Wc[c * NCLS + k];
            b10[k] = bsum;
        }
    }
}

__global__ __launch_bounds__(128)
void atom_encoder_alpha(const int* __restrict__ feats, const float* __restrict__ emb,
                        const float* __restrict__ wsrc0, const float* __restrict__ wdst0,
                        float* __restrict__ x, float* __restrict__ asrc,
                        float* __restrict__ adst) {
    int n = blockIdx.x;
    int t = threadIdx.x;
    __shared__ int f[NF];
    __shared__ float part[2][8];
    if (t < NF) f[t] = feats[n * NF + t];
    __syncthreads();
    float acc = 0.f;
#pragma unroll
    for (int i = 0; i < NF; ++i)
        acc += emb[(i * VOCAB + f[i]) * D + t];
    x[n * D + t] = acc;
    float dots[8];
#pragma unroll
    for (int h = 0; h < NH; ++h) {
        dots[h]     = acc * wsrc0[h * D + t];
        dots[4 + h] = acc * wdst0[h * D + t];
    }
#pragma unroll
    for (int off = 32; off; off >>= 1)
#pragma unroll
        for (int k = 0; k < 8; ++k) dots[k] += __shfl_down(dots[k], off);
    if ((t & 63) == 0) {
        int w = t >> 6;
#pragma unroll
        for (int k = 0; k < 8; ++k) part[w][k] = dots[k];
    }
    __syncthreads();
    if (t < 8) {
        float v = part[0][t] + part[1][t];
        if (t < 4) asrc[n * NH + t] = v;
        else       adst[n * NH + (t - 4)] = v;
    }
}

__global__ __launch_bounds__(256)
void alphas2(const float* __restrict__ X, const float* __restrict__ wsrc,
             const float* __restrict__ wdst, float* __restrict__ asrc,
             float* __restrict__ adst) {
    int n = blockIdx.x * 4 + (threadIdx.x >> 6);
    int lane = threadIdx.x & 63;
    float x0 = X[n * D + lane], x1 = X[n * D + lane + 64];
#pragma unroll
    for (int h = 0; h < NH; ++h) {
        float s = x0 * wsrc[h * D + lane] + x1 * wsrc[h * D + lane + 64];
        float d = x0 * wdst[h * D + lane] + x1 * wdst[h * D + lane + 64];
#pragma unroll
        for (int off = 32; off; off >>= 1) {
            s += __shfl_down(s, off);
            d += __shfl_down(d, off);
        }
        if (lane == 0) { asrc[n * NH + h] = s; adst[n * NH + h] = d; }
    }
}

__global__ __launch_bounds__(128)
void gat_agg(const int* __restrict__ csr_src, const int* __restrict__ rowstart,
             const int* __restrict__ degA, const float* __restrict__ asr,
             const float* __restrict__ adr, const float* __restrict__ X,
             unsigned* __restrict__ aggh, unsigned* __restrict__ aggl) {
    int n = blockIdx.x;
    int t = threadIdx.x;
    int deg = degA[n];
    int start = rowstart[n];
    __shared__ float smax[NH];
    __shared__ float sinv[NH];
    __shared__ float lal[128][NH];
    __shared__ int lsrc[128];
    int h = t >> 5, i = t & 31;
    float ad_h = adr[n * NH + h];
    float mx = NEG_BIG;
    for (int j = i; j < deg; j += 32) {
        int s = csr_src[start + j];
        float v = asr[s * NH + h] + ad_h;
        v = v >= 0.f ? v : 0.2f * v;
        mx = fmaxf(mx, v);
    }
#pragma unroll
    for (int off = 16; off; off >>= 1) mx = fmaxf(mx, __shfl_xor(mx, off));
    if (i == 0) smax[h] = mx;
    __syncthreads();
    float m = smax[h];
    float ss = 0.f;
    for (int j = i; j < deg; j += 32) {
        int s = csr_src[start + j];
        float v = asr[s * NH + h] + ad_h;
        v = v >= 0.f ? v : 0.2f * v;
        ss += __expf(v - m);
    }
#pragma unroll
    for (int off = 16; off; off >>= 1) ss += __shfl_xor(ss, off);
    if (i == 0) sinv[h] = 0.25f / (ss + 1e-16f);
    __syncthreads();
    float fm0 = smax[0], fm1 = smax[1], fm2 = smax[2], fm3 = smax[3];
    float fi0 = sinv[0], fi1 = sinv[1], fi2 = sinv[2], fi3 = sinv[3];
    float a0 = adr[n * NH + 0], a1 = adr[n * NH + 1];
    float a2 = adr[n * NH + 2], a3 = adr[n * NH + 3];
    float acc0 = 0.f, acc1 = 0.f, acc2 = 0.f, acc3 = 0.f;
    for (int cb = 0; cb < deg; cb += 128) {
        int cl = deg - cb; if (cl > 128) cl = 128;
        if (t < cl) {
            int sn = csr_src[start + cb + t];
            float4 av = *(const float4*)(asr + sn * NH);
            float v0 = av.x + a0; v0 = v0 >= 0.f ? v0 : 0.2f * v0;
            float v1 = av.y + a1; v1 = v1 >= 0.f ? v1 : 0.2f * v1;
            float v2 = av.z + a2; v2 = v2 >= 0.f ? v2 : 0.2f * v2;
            float v3 = av.w + a3; v3 = v3 >= 0.f ? v3 : 0.2f * v3;
            lal[t][0] = __expf(v0 - fm0) * fi0;
            lal[t][1] = __expf(v1 - fm1) * fi1;
            lal[t][2] = __expf(v2 - fm2) * fi2;
            lal[t][3] = __expf(v3 - fm3) * fi3;
            lsrc[t] = sn;
        }
        __syncthreads();
#pragma unroll 4
        for (int j = 0; j < cl; ++j) {
            float xv = X[(size_t)lsrc[j] * D + t];
            float4 w = *(const float4*)lal[j];
            acc0 += w.x * xv;
            acc1 += w.y * xv;
            acc2 += w.z * xv;
            acc3 += w.w * xv;
        }
        __syncthreads();
    }
    unsigned short h0 = f2bf(acc0), h1 = f2bf(acc1), h2 = f2bf(acc2), h3 = f2bf(acc3);
    unsigned short l0 = f2bf(acc0 - bf2f(h0)), l1 = f2bf(acc1 - bf2f(h1));
    unsigned short l2 = f2bf(acc2 - bf2f(h2)), l3 = f2bf(acc3 - bf2f(h3));
    size_t base = ((size_t)n * HC + t * 4) >> 1;
    uint2 uh = make_uint2((unsigned)h0 | ((unsigned)h1 << 16),
                          (unsigned)h2 | ((unsigned)h3 << 16));
    uint2 ul = make_uint2((unsigned)l0 | ((unsigned)l1 << 16),
                          (unsigned)l2 | ((unsigned)l3 << 16));
    *(uint2*)(aggh + base) = uh;
    *(uint2*)(aggl + base) = ul;
}

__global__ __launch_bounds__(64)
void gemm_mfma(const unsigned short* __restrict__ Ah, const unsigned short* __restrict__ Al,
               const unsigned short* __restrict__ Bth, const unsigned short* __restrict__ Btl,
               const float* __restrict__ bias, float* __restrict__ Out, int do_gelu) {
    int lane = threadIdx.x;
    int m0 = blockIdx.x * 16;
    int n0 = blockIdx.y * 64;
    int r = lane & 15;
    int g = lane >> 4;
    const bf16x8* ah = (const bf16x8*)(Ah + (size_t)(m0 + r) * HC + g * 8);
    const bf16x8* al = (const bf16x8*)(Al + (size_t)(m0 + r) * HC + g * 8);
    const bf16x8* bh0 = (const bf16x8*)(Bth + (size_t)(n0 + 0 * 16 + r) * HC + g * 8);
    const bf16x8* bh1 = (const bf16x8*)(Bth + (size_t)(n0 + 1 * 16 + r) * HC + g * 8);
    const bf16x8* bh2 = (const bf16x8*)(Bth + (size_t)(n0 + 2 * 16 + r) * HC + g * 8);
    const bf16x8* bh3 = (const bf16x8*)(Bth + (size_t)(n0 + 3 * 16 + r) * HC + g * 8);
    const bf16x8* bl0 = (const bf16x8*)(Btl + (size_t)(n0 + 0 * 16 + r) * HC + g * 8);
    const bf16x8* bl1 = (const bf16x8*)(Btl + (size_t)(n0 + 1 * 16 + r) * HC + g * 8);
    const bf16x8* bl2 = (const bf16x8*)(Btl + (size_t)(n0 + 2 * 16 + r) * HC + g * 8);
    const bf16x8* bl3 = (const bf16x8*)(Btl + (size_t)(n0 + 3 * 16 + r) * HC + g * 8);
    f32x4 acc[4];
#pragma unroll
    for (int q = 0; q < 4; ++q) acc[q] = (f32x4){0.f, 0.f, 0.f, 0.f};
#pragma unroll 2
    for (int ks = 0; ks < HC / 32; ++ks) {
        bf16x8 a_h = ah[ks * 4];
        bf16x8 a_l = al[ks * 4];
        bf16x8 b;
        b = bh0[ks * 4];
        acc[0] = __builtin_amdgcn_mfma_f32_16x16x32_bf16(a_h, b, acc[0], 0, 0, 0);
        acc[0] = __builtin_amdgcn_mfma_f32_16x16x32_bf16(a_l, b, acc[0], 0, 0, 0);
        b = bl0[ks * 4];
        acc[0] = __builtin_amdgcn_mfma_f32_16x16x32_bf16(a_h, b, acc[0], 0, 0, 0);
        b = bh1[ks * 4];
        acc[1] = __builtin_amdgcn_mfma_f32_16x16x32_bf16(a_h, b, acc[1], 0, 0, 0);
        acc[1] = __builtin_amdgcn_mfma_f32_16x16x32_bf16(a_l, b, acc[1], 0, 0, 0);
        b = bl1[ks * 4];
        acc[1] = __builtin_amdgcn_mfma_f32_16x16x32_bf16(a_h, b, acc[1], 0, 0, 0);
        b = bh2[ks * 4];
        acc[2] = __builtin_amdgcn_mfma_f32_16x16x32_bf16(a_h, b, acc[2], 0, 0, 0);
        acc[2] = __builtin_amdgcn_mfma_f32_16x16x32_bf16(a_l, b, acc[2], 0, 0, 0);
        b = bl2[ks * 4];
        acc[2] = __builtin_amdgcn_mfma_f32_16x16x32_bf16(a_h, b, acc[2], 0, 0, 0);
        b = bh3[ks * 4];
        acc[3] = __builtin_amdgcn_mfma_f32_16x16x32_bf16(a_h, b, acc[3], 0, 0, 0);
        acc[3] = __builtin_amdgcn_mfma_f32_16x16x32_bf16(a_l, b, acc[3], 0, 0, 0);
        b = bl3[ks * 4];
        acc[3] = __builtin_amdgcn_mfma_f32_16x16x32_bf16(a_h, b, acc[3], 0, 0, 0);
    }
#pragma unroll
    for (int q = 0; q < 4; ++q) {
#pragma unroll
        for (int i = 0; i < 4; ++i) {
            int row = m0 + g * 4 + i;
            int col = n0 + q * 16 + r;
            float v = acc[q][i] + bias[col];
            if (do_gelu) {
                float u = 0.7978845608028654f * (v + 0.044715f * v * v * v);
                v = 0.5f * v * (1.f + tanhf(u));
            }
            Out[(size_t)row * D + col] = v;
        }
    }
}

__global__ __launch_bounds__(512)
void pool512(const unsigned short* __restrict__ Ah, const unsigned short* __restrict__ Al,
             float* __restrict__ p) {
    int t = threadIdx.x;
    int chunk = (NN + gridDim.x - 1) / gridDim.x;
    int n0 = blockIdx.x * chunk;
    int n1 = n0 + chunk; if (n1 > NN) n1 = NN;
    float acc = 0.f;
    for (int n = n0; n < n1; ++n)
        acc += bf2f(Ah[(size_t)n * HC + t]) + bf2f(Al[(size_t)n * HC + t]);
    atomicAdd(p + t, acc);
}

__global__ __launch_bounds__(640)
void final10(const float* __restrict__ p512, const float* __restrict__ M,
             const float* __restrict__ b10, float* __restrict__ out) {
    int k = threadIdx.x >> 6;
    int lane = threadIdx.x & 63;
    float acc = 0.f;
#pragma unroll
    for (int i = 0; i < HC / 64; ++i) {
        int j = lane + i * 64;
        acc += p512[j] * M[(size_t)k * HC + j];
    }
#pragma unroll
    for (int off = 32; off; off >>= 1) acc += __shfl_down(acc, off);
    if (lane == 0) out[k] = b10[k] + acc * (1.0f / NN);
}

extern "C" void kernel_launch(void* const* d_in, const int* in_sizes, int n_in,
                              void* d_out, int out_size, void* d_ws, size_t ws_size,
                              hipStream_t stream) {
    const int*   feats = (const int*)d_in[0];
    const int*   edges = (const int*)d_in[1];
    const float* emb   = (const float*)d_in[2];
    const float* W     = (const float*)d_in[3];
    const float* asrcW = (const float*)d_in[4];
    const float* adstW = (const float*)d_in[5];
    const float* bias  = (const float*)d_in[6];
    const float* Wc    = (const float*)d_in[7];
    const float* bc    = (const float*)d_in[8];
    float* out = (float*)d_out;

    const int* srcp = edges;
    const int* dstp = edges + NE;

    char* ws = (char*)d_ws;
    size_t off = 0;
    unsigned short* aggh = (unsigned short*)(ws + off); off += (size_t)NN * HC * 2;
    unsigned short* aggl = (unsigned short*)(ws + off); off += (size_t)NN * HC * 2;
    float* xb0    = (float*)(ws + off); off += (size_t)NN * D * 4;
    float* xb1    = (float*)(ws + off); off += (size_t)NN * D * 4;
    float* asrc   = (float*)(ws + off); off += (size_t)NN * NH * 4;
    float* adst   = (float*)(ws + off); off += (size_t)NN * NH * 4;
    int*   deg    = (int*)(ws + off);   off += (size_t)NN * 4;
    int*   rowst  = (int*)(ws + off);   off += (size_t)NN * 4;
    int*   cursor = (int*)(ws + off);   off += (size_t)NN * 4;
    int*   csrsrc = (int*)(ws + off);   off += (size_t)NE * 4;
    float* wsrcb  = (float*)(ws + off); off += (size_t)NL * NH * D * 4;
    float* wdstb  = (float*)(ws + off); off += (size_t)NL * NH * D * 4;
    unsigned short* Bth = (unsigned short*)(ws + off); off += (size_t)2 * 128 * HC * 2;
    unsigned short* Btl = (unsigned short*)(ws + off); off += (size_t)2 * 128 * HC * 2;
    float* Mhead  = (float*)(ws + off); off += (size_t)NCLS * HC * 4;
    float* b10    = (float*)(ws + off); off += (size_t)((NCLS + 127) / 128) * 128 * 4;
    float* p512   = (float*)(ws + off); off += HC * 4;
    int*   blocksum = (int*)(ws + off); off += (size_t)MB * 4;
    int*   blockoff = (int*)(ws + off); off += (size_t)MB * 4;

    MegaParams mp;
    mp.feats = feats; mp.srcp = srcp; mp.dstp = dstp;
    mp.emb = emb; mp.W = W; mp.asrcW = asrcW; mp.adstW = adstW;
    mp.bias = bias; mp.Wc = Wc; mp.bc = bc; mp.out = out;
    mp.aggh = aggh; mp.aggl = aggl; mp.xb0 = xb0; mp.xb1 = xb1;
    mp.asrc = asrc; mp.adst = adst; mp.deg = deg; mp.rowst = rowst;
    mp.cursor = cursor; mp.csrsrc = csrsrc; mp.blocksum = blocksum;
    mp.blockoff = blockoff; mp.wsrcb = wsrcb; mp.wdstb = wdstb;
    mp.Bth = Bth; mp.Btl = Btl; mp.Mhead = Mhead; mp.b10 = b10; mp.p512 = p512;

    void* args[] = {(void*)&mp};
    hipError_t err = hipLaunchCooperativeKernel((const void*)mega, dim3(MB), dim3(256),
                                                args, 0, stream);
    if (err == hipSuccess) return;

    // ---------- fallback: proven R9 multi-kernel path ----------
    hipMemsetAsync(deg, 0, (size_t)NN * 4, stream);
    hist<<<(NE + 255) / 256, 256, 0, stream>>>(dstp, deg);
    scan_deg<<<1, SCAN_T, 0, stream>>>(deg, rowst, cursor);
    scatter<<<(NE + 255) / 256, 256, 0, stream>>>(srcp, dstp, cursor, csrsrc);
    prep_all<<<290, 512, 0, stream>>>(W, asrcW, adstW, Wc, bias, bc,
                                      wsrcb, wdstb, Bth, Btl, Mhead, b10, p512);
    atom_encoder_alpha<<<NN, 128, 0, stream>>>(feats, emb, wsrcb, wdstb,
                                               xb0, asrc, adst);
    float* xin = xb0;
    float* xout = xb1;
    for (int l = 0; l < 2; ++l) {
        if (l > 0)
            alphas2<<<NN / 4, 256, 0, stream>>>(xin, wsrcb + (size_t)l * NH * D,
                                                wdstb + (size_t)l * NH * D, asrc, adst);
        gat_agg<<<NN, 128, 0, stream>>>(csrsrc, rowst, deg, asrc, adst, xin,
                                        (unsigned*)aggh, (unsigned*)aggl);
        gemm_mfma<<<dim3(NN / 16, 2), 64, 0, stream>>>(
            aggh, aggl, Bth + (size_t)l * 128 * HC, Btl + (size_t)l * 128 * HC,
            bias + (size_t)l * D, xout, 1);
        float* tmp = xin; xin = xout; xout = tmp;
    }
    alphas2<<<NN / 4, 256, 0, stream>>>(xin, wsrcb + (size_t)2 * NH * D,
                                        wdstb + (size_t)2 * NH * D, asrc, adst);
    gat_agg<<<NN, 128, 0, stream>>>(csrsrc, rowst, deg, asrc, adst, xin,
                                    (unsigned*)aggh, (unsigned*)aggl);
    pool512<<<100, 512, 0, stream>>>(aggh, aggl, p512);
    final10<<<1, 640, 0, stream>>>(p512, Mhead, b10, out);
}

// Round 11
// 314.004 us; speedup vs baseline: 3.6904x; 3.6904x over previous
//
#include <hip/hip_runtime.h>
#include <hip/hip_bf16.h>
#include <math.h>

#define NN 10000      // nodes
#define NE 160000     // edges
#define NF 9          // atom features
#define VOCAB 128
#define D 128
#define NH 4          // heads
#define C 128
#define HC 512        // NH*C
#define NCLS 10
#define NL 3

#define NEG_BIG (-1e30f)   // finite -inf substitute

typedef __attribute__((ext_vector_type(8))) short bf16x8;
typedef __attribute__((ext_vector_type(4))) float f32x4;

__device__ __forceinline__ unsigned short f2bf(float f) {
    unsigned u = __float_as_uint(f);
    unsigned r = ((u >> 16) & 1u) + 0x7FFFu;
    return (unsigned short)((u + r) >> 16);
}
__device__ __forceinline__ float bf2f(unsigned short h) {
    return __uint_as_float(((unsigned)h) << 16);
}

// ---- CSR build: histogram of dst ----
__global__ __launch_bounds__(256)
void hist(const int* __restrict__ dst, int* __restrict__ deg) {
    int e = blockIdx.x * 256 + threadIdx.x;
    if (e < NE) atomicAdd(&deg[dst[e]], 1);
}

// ---- CSR build: one-block exclusive scan of deg[NN] -> rowstart, cursor ----
#define SCAN_T 1024
#define SCAN_PER ((NN + SCAN_T - 1) / SCAN_T)   // 10
__global__ __launch_bounds__(SCAN_T)
void scan_deg(const int* __restrict__ deg, int* __restrict__ rowstart,
              int* __restrict__ cursor) {
    __shared__ int part[SCAN_T];
    int t = threadIdx.x;
    int base = t * SCAN_PER;
    int vals[SCAN_PER];
    int loc = 0;
#pragma unroll
    for (int i = 0; i < SCAN_PER; ++i) {
        int idx = base + i;
        int v = (idx < NN) ? deg[idx] : 0;
        vals[i] = v;
        loc += v;
    }
    part[t] = loc;
    __syncthreads();
    for (int off = 1; off < SCAN_T; off <<= 1) {
        int y = (t >= off) ? part[t - off] : 0;
        __syncthreads();
        part[t] += y;
        __syncthreads();
    }
    int run = part[t] - loc;   // exclusive prefix
#pragma unroll
    for (int i = 0; i < SCAN_PER; ++i) {
        int idx = base + i;
        if (idx < NN) { rowstart[idx] = run; cursor[idx] = run; }
        run += vals[i];
    }
}

// ---- CSR build: scatter src sorted by dst ----
__global__ __launch_bounds__(256)
void scatter(const int* __restrict__ src, const int* __restrict__ dst,
             int* __restrict__ cursor, int* __restrict__ csr_src) {
    int e = blockIdx.x * 256 + threadIdx.x;
    if (e < NE) {
        int p = atomicAdd(&cursor[dst[e]], 1);
        csr_src[p] = src[e];
    }
}

// ---- P: merged prep. blocks [0,24): att vecs; [24,280): W split; [280,290): head ----
__global__ __launch_bounds__(512)
void prep_all(const float* __restrict__ W, const float* __restrict__ as_,
              const float* __restrict__ ad_, const float* __restrict__ Wc,
              const float* __restrict__ biasA, const float* __restrict__ bc,
              float* __restrict__ wsrc, float* __restrict__ wdst,
              unsigned short* __restrict__ Bth, unsigned short* __restrict__ Btl,
              float* __restrict__ M, float* __restrict__ b10,
              float* __restrict__ p512, int* __restrict__ done) {
    int b = blockIdx.x;
    if (b < 24) {                       // prep_att: 128 active threads
        int k = threadIdx.x;
        if (k >= 128) return;
        int l = b >> 3;
        int r = b & 7;
        int h = r >> 1;
        int side = r & 1;
        const float* av = (side ? ad_ : as_) + (size_t)(l * NH + h) * C;
        const float* wrow = W + (size_t)l * D * HC + (size_t)k * HC + h * C;
        float acc = 0.f;
#pragma unroll 4
        for (int c = 0; c < C; ++c) acc += wrow[c] * av[c];
        float* o = (side ? wdst : wsrc) + (size_t)(l * NH + h) * D + k;
        *o = acc;
    } else if (b < 280) {               // prep_w: j = d*4+h d-major split
        int bb = b - 24;
        int l = bb >> 7;
        int c = bb & 127;
        int j = threadIdx.x;
        float v = W[(size_t)l * D * HC + (size_t)(j >> 2) * HC + (j & 3) * C + c];
        unsigned short h = f2bf(v);
        unsigned short lo = f2bf(v - bf2f(h));
        size_t o = (size_t)(l * 128 + c) * HC + j;
        Bth[o] = h;
        Btl[o] = lo;
    } else {                            // prep_head
        int k = b - 280;
        int j = threadIdx.x;
        const float* W3 = W + (size_t)2 * D * HC;
        const float* bias3 = biasA + (size_t)2 * D;
        const float* wrow = W3 + (size_t)(j >> 2) * HC + (j & 3) * C;
        float acc = 0.f;
#pragma unroll 4
        for (int c = 0; c < C; ++c) acc += wrow[c] * Wc[c * NCLS + k];
        M[(size_t)k * HC + j] = acc;
        if (k == 0) p512[j] = 0.f;
        if (k == 0 && j == 0) *done = 0;
        if (j == 0) {
            float bsum = bc[k];
            for (int c = 0; c < C; ++c) bsum += bias3[c] * Wc[c * NCLS + k];
            b10[k] = bsum;
        }
    }
}

// ---- K0: atom encoder + layer-0 alphas fused (x in registers) ----
__global__ __launch_bounds__(128)
void atom_encoder_alpha(const int* __restrict__ feats, const float* __restrict__ emb,
                        const float* __restrict__ wsrc0, const float* __restrict__ wdst0,
                        float* __restrict__ x, float* __restrict__ asrc,
                        float* __restrict__ adst) {
    int n = blockIdx.x;
    int t = threadIdx.x;
    __shared__ int f[NF];
    __shared__ float part[2][8];
    if (t < NF) f[t] = feats[n * NF + t];
    __syncthreads();
    float acc = 0.f;
#pragma unroll
    for (int i = 0; i < NF; ++i)
        acc += emb[(i * VOCAB + f[i]) * D + t];
    x[n * D + t] = acc;

    float dots[8];
#pragma unroll
    for (int h = 0; h < NH; ++h) {
        dots[h]     = acc * wsrc0[h * D + t];
        dots[4 + h] = acc * wdst0[h * D + t];
    }
#pragma unroll
    for (int off = 32; off; off >>= 1)
#pragma unroll
        for (int k = 0; k < 8; ++k) dots[k] += __shfl_down(dots[k], off);
    if ((t & 63) == 0) {
        int w = t >> 6;
#pragma unroll
        for (int k = 0; k < 8; ++k) part[w][k] = dots[k];
    }
    __syncthreads();
    if (t < 8) {
        float v = part[0][t] + part[1][t];
        if (t < 4) asrc[n * NH + t] = v;
        else       adst[n * NH + (t - 4)] = v;
    }
}

// ---- K3: per-dst softmax (two-pass) + aggregation -> agg bf16 hi/lo ----
__global__ __launch_bounds__(128)
void gat_agg(const int* __restrict__ csr_src, const int* __restrict__ rowstart,
             const int* __restrict__ degA, const float* __restrict__ asr,
             const float* __restrict__ adr, const float* __restrict__ X,
             unsigned* __restrict__ aggh, unsigned* __restrict__ aggl) {
    int n = blockIdx.x;
    int t = threadIdx.x;
    int deg = degA[n];
    int start = rowstart[n];

    __shared__ float smax[NH];
    __shared__ float sinv[NH];
    __shared__ float lal[128][NH];
    __shared__ int lsrc[128];

    int h = t >> 5, i = t & 31;
    float ad_h = adr[n * NH + h];
    float mx = NEG_BIG;
    for (int j = i; j < deg; j += 32) {
        int s = csr_src[start + j];
        float v = asr[s * NH + h] + ad_h;
        v = v >= 0.f ? v : 0.2f * v;
        mx = fmaxf(mx, v);
    }
#pragma unroll
    for (int off = 16; off; off >>= 1) mx = fmaxf(mx, __shfl_xor(mx, off));
    if (i == 0) smax[h] = mx;
    __syncthreads();
    float m = smax[h];
    float ss = 0.f;
    for (int j = i; j < deg; j += 32) {
        int s = csr_src[start + j];
        float v = asr[s * NH + h] + ad_h;
        v = v >= 0.f ? v : 0.2f * v;
        ss += __expf(v - m);
    }
#pragma unroll
    for (int off = 16; off; off >>= 1) ss += __shfl_xor(ss, off);
    if (i == 0) sinv[h] = 0.25f / (ss + 1e-16f);
    __syncthreads();

    float fm0 = smax[0], fm1 = smax[1], fm2 = smax[2], fm3 = smax[3];
    float fi0 = sinv[0], fi1 = sinv[1], fi2 = sinv[2], fi3 = sinv[3];
    float a0 = adr[n * NH + 0], a1 = adr[n * NH + 1];
    float a2 = adr[n * NH + 2], a3 = adr[n * NH + 3];
    float acc0 = 0.f, acc1 = 0.f, acc2 = 0.f, acc3 = 0.f;

    for (int cb = 0; cb < deg; cb += 128) {
        int cl = deg - cb; if (cl > 128) cl = 128;
        if (t < cl) {
            int sn = csr_src[start + cb + t];
            float4 av = *(const float4*)(asr + sn * NH);
            float v0 = av.x + a0; v0 = v0 >= 0.f ? v0 : 0.2f * v0;
            float v1 = av.y + a1; v1 = v1 >= 0.f ? v1 : 0.2f * v1;
            float v2 = av.z + a2; v2 = v2 >= 0.f ? v2 : 0.2f * v2;
            float v3 = av.w + a3; v3 = v3 >= 0.f ? v3 : 0.2f * v3;
            lal[t][0] = __expf(v0 - fm0) * fi0;
            lal[t][1] = __expf(v1 - fm1) * fi1;
            lal[t][2] = __expf(v2 - fm2) * fi2;
            lal[t][3] = __expf(v3 - fm3) * fi3;
            lsrc[t] = sn;
        }
        __syncthreads();
#pragma unroll 4
        for (int j = 0; j < cl; ++j) {
            float xv = X[(size_t)lsrc[j] * D + t];
            float4 w = *(const float4*)lal[j];
            acc0 += w.x * xv;
            acc1 += w.y * xv;
            acc2 += w.z * xv;
            acc3 += w.w * xv;
        }
        __syncthreads();
    }

    unsigned short h0 = f2bf(acc0), h1 = f2bf(acc1), h2 = f2bf(acc2), h3 = f2bf(acc3);
    unsigned short l0 = f2bf(acc0 - bf2f(h0)), l1 = f2bf(acc1 - bf2f(h1));
    unsigned short l2 = f2bf(acc2 - bf2f(h2)), l3 = f2bf(acc3 - bf2f(h3));
    size_t base = ((size_t)n * HC + t * 4) >> 1;
    uint2 uh = make_uint2((unsigned)h0 | ((unsigned)h1 << 16),
                          (unsigned)h2 | ((unsigned)h3 << 16));
    uint2 ul = make_uint2((unsigned)l0 | ((unsigned)l1 << 16),
                          (unsigned)l2 | ((unsigned)l3 << 16));
    *(uint2*)(aggh + base) = uh;
    *(uint2*)(aggl + base) = ul;
}

// ---- K4: fused MFMA GEMM + next-layer alphas ----
// 128 thr / 2 waves; block computes 16 rows x 128 cols; epilogue computes
// next layer's 8 attention dots per row from the LDS-staged tile.
__global__ __launch_bounds__(128)
void gemm_mfma_alpha(const unsigned short* __restrict__ Ah, const unsigned short* __restrict__ Al,
                     const unsigned short* __restrict__ Bth, const unsigned short* __restrict__ Btl,
                     const float* __restrict__ bias,
                     const float* __restrict__ wsrcN, const float* __restrict__ wdstN,
                     float* __restrict__ Out, float* __restrict__ asrc,
                     float* __restrict__ adst) {
    __shared__ float s_out[16][132];   // +4 pad: dot loop 2-way bank conflict only
    int tid = threadIdx.x;
    int lane = tid & 63;
    int wvid = tid >> 6;               // wave 0: cols 0-63, wave 1: cols 64-127
    int m0 = blockIdx.x * 16;
    int n0 = wvid * 64;
    int r = lane & 15;
    int g = lane >> 4;

    const bf16x8* ah = (const bf16x8*)(Ah + (size_t)(m0 + r) * HC + g * 8);
    const bf16x8* al = (const bf16x8*)(Al + (size_t)(m0 + r) * HC + g * 8);
    const bf16x8* bh0 = (const bf16x8*)(Bth + (size_t)(n0 + 0 * 16 + r) * HC + g * 8);
    const bf16x8* bh1 = (const bf16x8*)(Bth + (size_t)(n0 + 1 * 16 + r) * HC + g * 8);
    const bf16x8* bh2 = (const bf16x8*)(Bth + (size_t)(n0 + 2 * 16 + r) * HC + g * 8);
    const bf16x8* bh3 = (const bf16x8*)(Bth + (size_t)(n0 + 3 * 16 + r) * HC + g * 8);
    const bf16x8* bl0 = (const bf16x8*)(Btl + (size_t)(n0 + 0 * 16 + r) * HC + g * 8);
    const bf16x8* bl1 = (const bf16x8*)(Btl + (size_t)(n0 + 1 * 16 + r) * HC + g * 8);
    const bf16x8* bl2 = (const bf16x8*)(Btl + (size_t)(n0 + 2 * 16 + r) * HC + g * 8);
    const bf16x8* bl3 = (const bf16x8*)(Btl + (size_t)(n0 + 3 * 16 + r) * HC + g * 8);

    f32x4 acc[4];
#pragma unroll
    for (int q = 0; q < 4; ++q) acc[q] = (f32x4){0.f, 0.f, 0.f, 0.f};

#pragma unroll 2
    for (int ks = 0; ks < HC / 32; ++ks) {
        bf16x8 a_h = ah[ks * 4];
        bf16x8 a_l = al[ks * 4];
        bf16x8 b;
        b = bh0[ks * 4];
        acc[0] = __builtin_amdgcn_mfma_f32_16x16x32_bf16(a_h, b, acc[0], 0, 0, 0);
        acc[0] = __builtin_amdgcn_mfma_f32_16x16x32_bf16(a_l, b, acc[0], 0, 0, 0);
        b = bl0[ks * 4];
        acc[0] = __builtin_amdgcn_mfma_f32_16x16x32_bf16(a_h, b, acc[0], 0, 0, 0);
        b = bh1[ks * 4];
        acc[1] = __builtin_amdgcn_mfma_f32_16x16x32_bf16(a_h, b, acc[1], 0, 0, 0);
        acc[1] = __builtin_amdgcn_mfma_f32_16x16x32_bf16(a_l, b, acc[1], 0, 0, 0);
        b = bl1[ks * 4];
        acc[1] = __builtin_amdgcn_mfma_f32_16x16x32_bf16(a_h, b, acc[1], 0, 0, 0);
        b = bh2[ks * 4];
        acc[2] = __builtin_amdgcn_mfma_f32_16x16x32_bf16(a_h, b, acc[2], 0, 0, 0);
        acc[2] = __builtin_amdgcn_mfma_f32_16x16x32_bf16(a_l, b, acc[2], 0, 0, 0);
        b = bl2[ks * 4];
        acc[2] = __builtin_amdgcn_mfma_f32_16x16x32_bf16(a_h, b, acc[2], 0, 0, 0);
        b = bh3[ks * 4];
        acc[3] = __builtin_amdgcn_mfma_f32_16x16x32_bf16(a_h, b, acc[3], 0, 0, 0);
        acc[3] = __builtin_amdgcn_mfma_f32_16x16x32_bf16(a_l, b, acc[3], 0, 0, 0);
        b = bl3[ks * 4];
        acc[3] = __builtin_amdgcn_mfma_f32_16x16x32_bf16(a_h, b, acc[3], 0, 0, 0);
    }

    // epilogue: bias + gelu; write global + LDS tile
#pragma unroll
    for (int q = 0; q < 4; ++q) {
#pragma unroll
        for (int i = 0; i < 4; ++i) {
            int row = g * 4 + i;
            int col = n0 + q * 16 + r;
            float v = acc[q][i] + bias[col];
            float u = 0.7978845608028654f * (v + 0.044715f * v * v * v);
            v = 0.5f * v * (1.f + tanhf(u));
            Out[(size_t)(m0 + row) * D + col] = v;
            s_out[row][col] = v;
        }
    }
    __syncthreads();

    // next-layer alphas: thread = (row, k); dot over 128 cols
    int row = tid >> 3;
    int k = tid & 7;
    const float* wvp = (k < 4) ? (wsrcN + k * D) : (wdstN + (k - 4) * D);
    float dacc = 0.f;
#pragma unroll 8
    for (int c = 0; c < 128; ++c) dacc += s_out[row][c] * wvp[c];
    if (k < 4) asrc[(m0 + row) * NH + k] = dacc;
    else       adst[(m0 + row) * NH + (k - 4)] = dacc;
}

// ---- K5: pool + final head fused (last-block-done pattern) ----
__global__ __launch_bounds__(512)
void pool_final(const unsigned short* __restrict__ Ah, const unsigned short* __restrict__ Al,
                const float* __restrict__ M, const float* __restrict__ b10,
                float* __restrict__ p, int* __restrict__ done, float* __restrict__ out) {
    int t = threadIdx.x;
    int chunk = (NN + gridDim.x - 1) / gridDim.x;
    int n0 = blockIdx.x * chunk;
    int n1 = n0 + chunk; if (n1 > NN) n1 = NN;
    float acc = 0.f;
    for (int n = n0; n < n1; ++n)
        acc += bf2f(Ah[(size_t)n * HC + t]) + bf2f(Al[(size_t)n * HC + t]);
    atomicAdd(p + t, acc);
    __threadfence();

    __shared__ int isLast;
    if (t == 0) {
        int old = atomicAdd(done, 1);
        isLast = (old == (int)gridDim.x - 1) ? 1 : 0;
    }
    __syncthreads();
    if (isLast) {
        __threadfence();
        int k = t >> 4, i = t & 15;
        if (k < NCLS) {
            float a2 = 0.f;
#pragma unroll 8
            for (int q = 0; q < HC / 16; ++q) {
                int j = i + q * 16;
                a2 += p[j] * M[(size_t)k * HC + j];
            }
#pragma unroll
            for (int off = 8; off; off >>= 1) a2 += __shfl_down(a2, off, 16);
            if (i == 0) out[k] = b10[k] + a2 * (1.0f / NN);
        }
    }
}

extern "C" void kernel_launch(void* const* d_in, const int* in_sizes, int n_in,
                              void* d_out, int out_size, void* d_ws, size_t ws_size,
                              hipStream_t stream) {
    const int*   feats = (const int*)d_in[0];
    const int*   edges = (const int*)d_in[1];
    const float* emb   = (const float*)d_in[2];
    const float* W     = (const float*)d_in[3];
    const float* asrcW = (const float*)d_in[4];
    const float* adstW = (const float*)d_in[5];
    const float* bias  = (const float*)d_in[6];
    const float* Wc    = (const float*)d_in[7];
    const float* bc    = (const float*)d_in[8];
    float* out = (float*)d_out;

    const int* srcp = edges;
    const int* dstp = edges + NE;

    char* ws = (char*)d_ws;
    size_t off = 0;
    unsigned short* aggh = (unsigned short*)(ws + off); off += (size_t)NN * HC * 2;
    unsigned short* aggl = (unsigned short*)(ws + off); off += (size_t)NN * HC * 2;
    float* xb0    = (float*)(ws + off); off += (size_t)NN * D * 4;
    float* xb1    = (float*)(ws + off); off += (size_t)NN * D * 4;
    float* asrc   = (float*)(ws + off); off += (size_t)NN * NH * 4;
    float* adst   = (float*)(ws + off); off += (size_t)NN * NH * 4;
    int*   deg    = (int*)(ws + off);   off += (size_t)NN * 4;
    int*   rowst  = (int*)(ws + off);   off += (size_t)NN * 4;
    int*   cursor = (int*)(ws + off);   off += (size_t)NN * 4;
    int*   csrsrc = (int*)(ws + off);   off += (size_t)NE * 4;
    float* wsrcb  = (float*)(ws + off); off += (size_t)NL * NH * D * 4;
    float* wdstb  = (float*)(ws + off); off += (size_t)NL * NH * D * 4;
    unsigned short* Bth = (unsigned short*)(ws + off); off += (size_t)2 * 128 * HC * 2;
    unsigned short* Btl = (unsigned short*)(ws + off); off += (size_t)2 * 128 * HC * 2;
    float* Mhead  = (float*)(ws + off); off += (size_t)NCLS * HC * 4;
    float* b10    = (float*)(ws + off); off += NCLS * 4;
    float* p512   = (float*)(ws + off); off += HC * 4;
    int*   done   = (int*)(ws + off);   off += 4;

    // ---- prep: CSR + merged weight-prep ----
    hipMemsetAsync(deg, 0, (size_t)NN * 4, stream);
    hist<<<(NE + 255) / 256, 256, 0, stream>>>(dstp, deg);
    scan_deg<<<1, SCAN_T, 0, stream>>>(deg, rowst, cursor);
    scatter<<<(NE + 255) / 256, 256, 0, stream>>>(srcp, dstp, cursor, csrsrc);
    prep_all<<<290, 512, 0, stream>>>(W, asrcW, adstW, Wc, bias, bc,
                                      wsrcb, wdstb, Bth, Btl, Mhead, b10, p512, done);

    // encoder + layer-0 alphas
    atom_encoder_alpha<<<NN, 128, 0, stream>>>(feats, emb, wsrcb, wdstb,
                                               xb0, asrc, adst);

    // layer 0: agg -> gemm(+alpha for layer 1)
    gat_agg<<<NN, 128, 0, stream>>>(csrsrc, rowst, deg, asrc, adst, xb0,
                                    (unsigned*)aggh, (unsigned*)aggl);
    gemm_mfma_alpha<<<NN / 16, 128, 0, stream>>>(
        aggh, aggl, Bth, Btl, bias,
        wsrcb + (size_t)1 * NH * D, wdstb + (size_t)1 * NH * D,
        xb1, asrc, adst);

    // layer 1: agg -> gemm(+alpha for layer 2)
    gat_agg<<<NN, 128, 0, stream>>>(csrsrc, rowst, deg, asrc, adst, xb1,
                                    (unsigned*)aggh, (unsigned*)aggl);
    gemm_mfma_alpha<<<NN / 16, 128, 0, stream>>>(
        aggh, aggl, Bth + (size_t)128 * HC, Btl + (size_t)128 * HC, bias + (size_t)1 * D,
        wsrcb + (size_t)2 * NH * D, wdstb + (size_t)2 * NH * D,
        xb0, asrc, adst);

    // layer 2: agg -> pool+head (GEMM commuted past mean)
    gat_agg<<<NN, 128, 0, stream>>>(csrsrc, rowst, deg, asrc, adst, xb0,
                                    (unsigned*)aggh, (unsigned*)aggl);
    pool_final<<<100, 512, 0, stream>>>(aggh, aggl, Mhead, b10, p512, done, out);
}